// Round 3
// baseline (638.761 us; speedup 1.0000x reference)
//
#include <hip/hip_runtime.h>

#define N_NODES 100000
#define N_EDGES 1600000
#define DIM 64
#define NEG_SLOPE 0.01f

// ------ fused: degree histogram + linked-list build (coalesced next[] write) ------
__global__ void build_ll(const int* __restrict__ dst, int* __restrict__ counts,
                         int* __restrict__ head, int* __restrict__ next) {
    int e = blockIdx.x * blockDim.x + threadIdx.x;
    if (e >= N_EDGES) return;
    int d = dst[e];
    atomicAdd(&counts[d], 1);
    next[e] = atomicExch(&head[d], e);
}

// ---------------- 3-phase exclusive scan over counts[N] ----------------
__global__ void scan_partial(const int* __restrict__ counts, int* __restrict__ bsums) {
    __shared__ int sm[1024];
    int i = blockIdx.x * 1024 + threadIdx.x;
    int v = (i < N_NODES) ? counts[i] : 0;
    sm[threadIdx.x] = v;
    __syncthreads();
    for (int s = 512; s > 0; s >>= 1) {
        if (threadIdx.x < s) sm[threadIdx.x] += sm[threadIdx.x + s];
        __syncthreads();
    }
    if (threadIdx.x == 0) bsums[blockIdx.x] = sm[0];
}

__global__ void scan_bsums(int* __restrict__ bsums, int nb) {
    __shared__ int sm[128];
    if ((int)threadIdx.x < nb) sm[threadIdx.x] = bsums[threadIdx.x];
    __syncthreads();
    if (threadIdx.x == 0) {
        int run = 0;
        for (int b = 0; b < nb; ++b) { int t = sm[b]; sm[b] = run; run += t; }
    }
    __syncthreads();
    if ((int)threadIdx.x < nb) bsums[threadIdx.x] = sm[threadIdx.x];
}

__global__ void scan_final(const int* __restrict__ counts, const int* __restrict__ bsums,
                           int* __restrict__ offsets, float* __restrict__ dinv) {
    __shared__ int sm[1024];
    int i = blockIdx.x * 1024 + threadIdx.x;
    int v = (i < N_NODES) ? counts[i] : 0;
    sm[threadIdx.x] = v;
    __syncthreads();
    for (int s = 1; s < 1024; s <<= 1) {
        int add = ((int)threadIdx.x >= s) ? sm[threadIdx.x - s] : 0;
        __syncthreads();
        sm[threadIdx.x] += add;
        __syncthreads();
    }
    int incl = sm[threadIdx.x];
    if (i < N_NODES) {
        offsets[i] = bsums[blockIdx.x] + (incl - v);
        dinv[i] = rsqrtf((float)(v + 1));   // deg includes self-loop
    }
    if (i == 0) offsets[N_NODES] = N_EDGES;
}

// ------ CSR fill via chain walk: per-node contiguous writes (no amplification) ------
__global__ void build_csr_walk(const int* __restrict__ head, const int* __restrict__ next,
                               const int* __restrict__ src, const int* __restrict__ offsets,
                               int* __restrict__ csr) {
    int d = blockIdx.x * blockDim.x + threadIdx.x;
    if (d >= N_NODES) return;
    int pos = offsets[d];
    int e = head[d];
    while (e >= 0) {
        csr[pos++] = src[e];
        e = next[e];
    }
}

// ---------------- fp32 matmul + dinv scale: G[i,:] = dinv[i] * (X[i,:] @ W) ----------------
// Block = 256 threads handles 64 rows. In-place safe (stages its 64 rows to LDS
// behind a barrier before any store).
__global__ __launch_bounds__(256) void mm_kernel(const float* X, const float* __restrict__ W,
                                                 const float* __restrict__ dinv, float* G) {
    __shared__ float xs[64][68];   // +4 pad: r-groups land on distinct banks
    __shared__ float ws[64][64];
    const int t = threadIdx.x;
    const int rbase = blockIdx.x * 64;

    const float4* Wv = (const float4*)W;
    for (int i = t; i < 1024; i += 256)
        ((float4*)&ws[0][0])[i] = Wv[i];

    for (int i = t; i < 1024; i += 256) {
        int r = i >> 4, kb = i & 15;
        int row = rbase + r;
        float4 xv = make_float4(0.f, 0.f, 0.f, 0.f);
        if (row < N_NODES) xv = *(const float4*)(X + row * DIM + kb * 4);
        *(float4*)&xs[r][kb * 4] = xv;
    }
    __syncthreads();

    const int c4 = (t & 15) * 4;
    const int r0 = t >> 4;
    float4 a0 = make_float4(0.f, 0.f, 0.f, 0.f), a1 = a0, a2 = a0, a3 = a0;

#pragma unroll 4
    for (int kb = 0; kb < 16; ++kb) {
        float x0[4], x1[4], x2[4], x3[4];
        *(float4*)x0 = *(const float4*)&xs[r0][kb * 4];
        *(float4*)x1 = *(const float4*)&xs[r0 + 16][kb * 4];
        *(float4*)x2 = *(const float4*)&xs[r0 + 32][kb * 4];
        *(float4*)x3 = *(const float4*)&xs[r0 + 48][kb * 4];
#pragma unroll
        for (int j = 0; j < 4; ++j) {
            float4 wv = *(const float4*)&ws[kb * 4 + j][c4];
            a0.x = fmaf(x0[j], wv.x, a0.x); a0.y = fmaf(x0[j], wv.y, a0.y);
            a0.z = fmaf(x0[j], wv.z, a0.z); a0.w = fmaf(x0[j], wv.w, a0.w);
            a1.x = fmaf(x1[j], wv.x, a1.x); a1.y = fmaf(x1[j], wv.y, a1.y);
            a1.z = fmaf(x1[j], wv.z, a1.z); a1.w = fmaf(x1[j], wv.w, a1.w);
            a2.x = fmaf(x2[j], wv.x, a2.x); a2.y = fmaf(x2[j], wv.y, a2.y);
            a2.z = fmaf(x2[j], wv.z, a2.z); a2.w = fmaf(x2[j], wv.w, a2.w);
            a3.x = fmaf(x3[j], wv.x, a3.x); a3.y = fmaf(x3[j], wv.y, a3.y);
            a3.z = fmaf(x3[j], wv.z, a3.z); a3.w = fmaf(x3[j], wv.w, a3.w);
        }
    }

    int row;
    row = rbase + r0;
    if (row < N_NODES) {
        float di = dinv[row];
        a0.x *= di; a0.y *= di; a0.z *= di; a0.w *= di;
        *(float4*)(G + row * DIM + c4) = a0;
    }
    row = rbase + r0 + 16;
    if (row < N_NODES) {
        float di = dinv[row];
        a1.x *= di; a1.y *= di; a1.z *= di; a1.w *= di;
        *(float4*)(G + row * DIM + c4) = a1;
    }
    row = rbase + r0 + 32;
    if (row < N_NODES) {
        float di = dinv[row];
        a2.x *= di; a2.y *= di; a2.z *= di; a2.w *= di;
        *(float4*)(G + row * DIM + c4) = a2;
    }
    row = rbase + r0 + 48;
    if (row < N_NODES) {
        float di = dinv[row];
        a3.x *= di; a3.y *= di; a3.z *= di; a3.w *= di;
        *(float4*)(G + row * DIM + c4) = a3;
    }
}

// ---------------- aggregate: wave per node, 4 edges in flight ----------------
// out[d,:] = leakyrelu( dinv[d] * (G[d,:] + sum_{e in N(d)} G[src[e],:]) + b )
// lane layout: slot = lane>>4 (4 edge slots), fc = (lane&15)*4 (float4 chunk).
__global__ __launch_bounds__(256) void agg_kernel(const float* __restrict__ G,
                                                  const int* __restrict__ csr,
                                                  const int* __restrict__ offsets,
                                                  const float* __restrict__ dinv,
                                                  const float* __restrict__ bias,
                                                  float* __restrict__ out) {
    int wid = (blockIdx.x * 256 + threadIdx.x) >> 6;   // node id
    if (wid >= N_NODES) return;
    const int lane = threadIdx.x & 63;
    const int slot = lane >> 4;          // 0..3
    const int fc   = (lane & 15) * 4;    // feature chunk base

    const int beg = offsets[wid], end = offsets[wid + 1];
    float4 acc = make_float4(0.f, 0.f, 0.f, 0.f);

    for (int e = beg + slot; e < end; e += 4) {
        int p = csr[e];
        float4 v = *(const float4*)(G + (size_t)p * DIM + fc);
        acc.x += v.x; acc.y += v.y; acc.z += v.z; acc.w += v.w;
    }

    // reduce the 4 slots (lanes fc_group + {0,16,32,48})
    acc.x += __shfl_xor(acc.x, 16, 64);
    acc.y += __shfl_xor(acc.y, 16, 64);
    acc.z += __shfl_xor(acc.z, 16, 64);
    acc.w += __shfl_xor(acc.w, 16, 64);
    acc.x += __shfl_xor(acc.x, 32, 64);
    acc.y += __shfl_xor(acc.y, 32, 64);
    acc.z += __shfl_xor(acc.z, 32, 64);
    acc.w += __shfl_xor(acc.w, 32, 64);

    if (slot == 0) {
        float di = dinv[wid];
        float4 g  = *(const float4*)(G + (size_t)wid * DIM + fc);
        float4 bv = *(const float4*)(bias + fc);
        float4 r;
        r.x = di * (acc.x + g.x) + bv.x;
        r.y = di * (acc.y + g.y) + bv.y;
        r.z = di * (acc.z + g.z) + bv.z;
        r.w = di * (acc.w + g.w) + bv.w;
        r.x = (r.x >= 0.f) ? r.x : NEG_SLOPE * r.x;
        r.y = (r.y >= 0.f) ? r.y : NEG_SLOPE * r.y;
        r.z = (r.z >= 0.f) ? r.z : NEG_SLOPE * r.z;
        r.w = (r.w >= 0.f) ? r.w : NEG_SLOPE * r.w;
        *(float4*)(out + (size_t)wid * DIM + fc) = r;
    }
}

extern "C" void kernel_launch(void* const* d_in, const int* in_sizes, int n_in,
                              void* d_out, int out_size, void* d_ws, size_t ws_size,
                              hipStream_t stream) {
    const float* x = (const float*)d_in[0];
    const int* ei = (const int*)d_in[1];
    const int* src = ei;
    const int* dst = ei + N_EDGES;
    const float* W[4] = {(const float*)d_in[2], (const float*)d_in[4],
                         (const float*)d_in[6], (const float*)d_in[8]};
    const float* b[4] = {(const float*)d_in[3], (const float*)d_in[5],
                         (const float*)d_in[7], (const float*)d_in[9]};
    float* out = (float*)d_out;

    char* ws = (char*)d_ws;
    size_t off = 0;
    auto alloc = [&](size_t bytes) -> void* {
        void* p = ws + off;
        off = (off + bytes + 255) & ~(size_t)255;
        return p;
    };
    float* A      = (float*)alloc((size_t)N_NODES * DIM * sizeof(float));
    int*   csr    = (int*)alloc((size_t)N_EDGES * sizeof(int));
    int*   next   = (int*)alloc((size_t)N_EDGES * sizeof(int));
    int*   head   = (int*)alloc((size_t)N_NODES * sizeof(int));
    int*   counts = (int*)alloc((size_t)N_NODES * sizeof(int));
    int*   offsets= (int*)alloc((size_t)(N_NODES + 1) * sizeof(int));
    float* dinv   = (float*)alloc((size_t)N_NODES * sizeof(float));
    int*   bsums  = (int*)alloc(128 * sizeof(int));

    const int NB = (N_NODES + 1023) / 1024;   // 98

    hipMemsetAsync(counts, 0, (size_t)N_NODES * sizeof(int), stream);
    hipMemsetAsync(head, 0xFF, (size_t)N_NODES * sizeof(int), stream);   // head = -1

    build_ll<<<(N_EDGES + 255) / 256, 256, 0, stream>>>(dst, counts, head, next);
    scan_partial<<<NB, 1024, 0, stream>>>(counts, bsums);
    scan_bsums<<<1, 128, 0, stream>>>(bsums, NB);
    scan_final<<<NB, 1024, 0, stream>>>(counts, bsums, offsets, dinv);
    build_csr_walk<<<(N_NODES + 255) / 256, 256, 0, stream>>>(head, next, src, offsets, csr);

    const int MM_GRID  = (N_NODES + 63) / 64;          // 1563
    const int AGG_GRID = (N_NODES * DIM + 255) / 256;  // 25000

    // L1: mm(x)->A, agg(A)->out
    mm_kernel<<<MM_GRID, 256, 0, stream>>>(x, W[0], dinv, A);
    agg_kernel<<<AGG_GRID, 256, 0, stream>>>(A, csr, offsets, dinv, b[0], out);
    // L2: mm(out)->out (in-place), agg(out)->A
    mm_kernel<<<MM_GRID, 256, 0, stream>>>(out, W[1], dinv, out);
    agg_kernel<<<AGG_GRID, 256, 0, stream>>>(out, csr, offsets, dinv, b[1], A);
    // L3: mm(A)->A (in-place), agg(A)->out
    mm_kernel<<<MM_GRID, 256, 0, stream>>>(A, W[2], dinv, A);
    agg_kernel<<<AGG_GRID, 256, 0, stream>>>(A, csr, offsets, dinv, b[2], out);
    // L4: mm(out)->A, agg(A)->out
    mm_kernel<<<MM_GRID, 256, 0, stream>>>(out, W[3], dinv, A);
    agg_kernel<<<AGG_GRID, 256, 0, stream>>>(A, csr, offsets, dinv, b[3], out);
}

// Round 4
// 500.001 us; speedup vs baseline: 1.2775x; 1.2775x over previous
//
#include <hip/hip_runtime.h>

#define N_NODES 100000
#define N_EDGES 1600000
#define DIM 64
#define NEG_SLOPE 0.01f

#define BNODES 128            // nodes per bucket
#define NBUCK 782             // ceil(100000/128)
#define BCAP 4096             // slab capacity per bucket (avg fill ~2046, max ~2300)
#define BLOCKS1 128           // scatter blocks
#define EPB ((N_EDGES + BLOCKS1 - 1) / BLOCKS1)   // 12500

// ---- pass 1: bucket scatter. One reservation atomic per (block,bucket). ----
// Entry packing: src (17 bits) | local_dst (7 bits) << 17.
__global__ __launch_bounds__(256) void bucket_scatter(const int* __restrict__ src,
                                                      const int* __restrict__ dst,
                                                      int* __restrict__ gcur,   // stride 16 (64B pad)
                                                      int* __restrict__ bdata) {
    __shared__ int cnt[NBUCK];
    __shared__ int base[NBUCK];
    const int tid = threadIdx.x;
    for (int i = tid; i < NBUCK; i += 256) cnt[i] = 0;
    __syncthreads();

    const int e0 = blockIdx.x * EPB;
    const int e1 = (e0 + EPB < N_EDGES) ? e0 + EPB : N_EDGES;

    for (int e = e0 + tid; e < e1; e += 256)
        atomicAdd(&cnt[dst[e] >> 7], 1);
    __syncthreads();

    for (int b = tid; b < NBUCK; b += 256) {
        int c = cnt[b];
        base[b] = c ? atomicAdd(&gcur[b * 16], c) : 0;
        cnt[b] = 0;
    }
    __syncthreads();

    for (int e = e0 + tid; e < e1; e += 256) {
        int d = dst[e];
        int b = d >> 7;
        int pos = base[b] + atomicAdd(&cnt[b], 1);
        bdata[(size_t)b * BCAP + pos] = src[e] | ((d & 127) << 17);
    }
}

// ---- exclusive scan of bucket sizes -> bucket csr base ----
__global__ void bucket_scan(const int* __restrict__ gcur, int* __restrict__ bbase) {
    __shared__ int sm[1024];
    const int tid = threadIdx.x;
    int v = (tid < NBUCK) ? gcur[tid * 16] : 0;
    sm[tid] = v;
    __syncthreads();
    for (int s = 1; s < 1024; s <<= 1) {
        int a = ((int)tid >= s) ? sm[tid - s] : 0;
        __syncthreads();
        sm[tid] += a;
        __syncthreads();
    }
    if (tid < NBUCK) bbase[tid] = sm[tid] - v;   // exclusive
}

// ---- pass 2: per-bucket counting sort -> offsets, dinv, csr (single-writer) ----
__global__ __launch_bounds__(256) void bucket_build(const int* __restrict__ bdata,
                                                    const int* __restrict__ gcur,
                                                    const int* __restrict__ bbase,
                                                    int* __restrict__ offsets,
                                                    float* __restrict__ dinv,
                                                    int* __restrict__ csr) {
    __shared__ int cnt[BNODES];
    __shared__ int excl[BNODES];
    const int tid = threadIdx.x;
    const int b = blockIdx.x;
    const int sz = gcur[b * 16];
    const int* bd = bdata + (size_t)b * BCAP;
    const int cbase = bbase[b];

    for (int i = tid; i < BNODES; i += 256) cnt[i] = 0;
    __syncthreads();
    for (int i = tid; i < sz; i += 256)
        atomicAdd(&cnt[bd[i] >> 17], 1);
    __syncthreads();
    if (tid == 0) {
        int run = 0;
        for (int j = 0; j < BNODES; ++j) { excl[j] = run; run += cnt[j]; }
    }
    __syncthreads();

    const int nb = b * BNODES;
    for (int i = tid; i < BNODES; i += 256) {
        int n = nb + i;
        if (n < N_NODES) {
            offsets[n] = cbase + excl[i];
            dinv[n] = rsqrtf((float)(cnt[i] + 1));   // deg incl self-loop
        }
    }
    if (b == NBUCK - 1 && tid == 0) offsets[N_NODES] = N_EDGES;

    for (int i = tid; i < BNODES; i += 256) cnt[i] = 0;   // reuse as cursor
    __syncthreads();
    for (int i = tid; i < sz; i += 256) {
        int v = bd[i];
        int l = v >> 17;
        int pos = cbase + excl[l] + atomicAdd(&cnt[l], 1);
        csr[pos] = v & 0x1FFFF;
    }
}

// ---------------- fp32 matmul + dinv scale: G[i,:] = dinv[i] * (X[i,:] @ W) ----------------
__global__ __launch_bounds__(256) void mm_kernel(const float* X, const float* __restrict__ W,
                                                 const float* __restrict__ dinv, float* G) {
    __shared__ float xs[64][68];
    __shared__ float ws[64][64];
    const int t = threadIdx.x;
    const int rbase = blockIdx.x * 64;

    const float4* Wv = (const float4*)W;
    for (int i = t; i < 1024; i += 256)
        ((float4*)&ws[0][0])[i] = Wv[i];

    for (int i = t; i < 1024; i += 256) {
        int r = i >> 4, kb = i & 15;
        int row = rbase + r;
        float4 xv = make_float4(0.f, 0.f, 0.f, 0.f);
        if (row < N_NODES) xv = *(const float4*)(X + row * DIM + kb * 4);
        *(float4*)&xs[r][kb * 4] = xv;
    }
    __syncthreads();

    const int c4 = (t & 15) * 4;
    const int r0 = t >> 4;
    float4 a0 = make_float4(0.f, 0.f, 0.f, 0.f), a1 = a0, a2 = a0, a3 = a0;

#pragma unroll 4
    for (int kb = 0; kb < 16; ++kb) {
        float x0[4], x1[4], x2[4], x3[4];
        *(float4*)x0 = *(const float4*)&xs[r0][kb * 4];
        *(float4*)x1 = *(const float4*)&xs[r0 + 16][kb * 4];
        *(float4*)x2 = *(const float4*)&xs[r0 + 32][kb * 4];
        *(float4*)x3 = *(const float4*)&xs[r0 + 48][kb * 4];
#pragma unroll
        for (int j = 0; j < 4; ++j) {
            float4 wv = *(const float4*)&ws[kb * 4 + j][c4];
            a0.x = fmaf(x0[j], wv.x, a0.x); a0.y = fmaf(x0[j], wv.y, a0.y);
            a0.z = fmaf(x0[j], wv.z, a0.z); a0.w = fmaf(x0[j], wv.w, a0.w);
            a1.x = fmaf(x1[j], wv.x, a1.x); a1.y = fmaf(x1[j], wv.y, a1.y);
            a1.z = fmaf(x1[j], wv.z, a1.z); a1.w = fmaf(x1[j], wv.w, a1.w);
            a2.x = fmaf(x2[j], wv.x, a2.x); a2.y = fmaf(x2[j], wv.y, a2.y);
            a2.z = fmaf(x2[j], wv.z, a2.z); a2.w = fmaf(x2[j], wv.w, a2.w);
            a3.x = fmaf(x3[j], wv.x, a3.x); a3.y = fmaf(x3[j], wv.y, a3.y);
            a3.z = fmaf(x3[j], wv.z, a3.z); a3.w = fmaf(x3[j], wv.w, a3.w);
        }
    }

    int row;
    row = rbase + r0;
    if (row < N_NODES) {
        float di = dinv[row];
        a0.x *= di; a0.y *= di; a0.z *= di; a0.w *= di;
        *(float4*)(G + row * DIM + c4) = a0;
    }
    row = rbase + r0 + 16;
    if (row < N_NODES) {
        float di = dinv[row];
        a1.x *= di; a1.y *= di; a1.z *= di; a1.w *= di;
        *(float4*)(G + row * DIM + c4) = a1;
    }
    row = rbase + r0 + 32;
    if (row < N_NODES) {
        float di = dinv[row];
        a2.x *= di; a2.y *= di; a2.z *= di; a2.w *= di;
        *(float4*)(G + row * DIM + c4) = a2;
    }
    row = rbase + r0 + 48;
    if (row < N_NODES) {
        float di = dinv[row];
        a3.x *= di; a3.y *= di; a3.z *= di; a3.w *= di;
        *(float4*)(G + row * DIM + c4) = a3;
    }
}

// ---------------- aggregate: wave per node, 4 edges in flight ----------------
// out[d,:] = leakyrelu( dinv[d] * (G[d,:] + sum_{e in N(d)} G[src[e],:]) + b )
__global__ __launch_bounds__(256) void agg_kernel(const float* __restrict__ G,
                                                  const int* __restrict__ csr,
                                                  const int* __restrict__ offsets,
                                                  const float* __restrict__ dinv,
                                                  const float* __restrict__ bias,
                                                  float* __restrict__ out) {
    int wid = (blockIdx.x * 256 + threadIdx.x) >> 6;   // node id
    if (wid >= N_NODES) return;
    const int lane = threadIdx.x & 63;
    const int slot = lane >> 4;          // 0..3
    const int fc   = (lane & 15) * 4;    // feature chunk base

    const int beg = offsets[wid], end = offsets[wid + 1];
    float4 acc = make_float4(0.f, 0.f, 0.f, 0.f);

    for (int e = beg + slot; e < end; e += 4) {
        int p = csr[e];
        float4 v = *(const float4*)(G + (size_t)p * DIM + fc);
        acc.x += v.x; acc.y += v.y; acc.z += v.z; acc.w += v.w;
    }

    acc.x += __shfl_xor(acc.x, 16, 64);
    acc.y += __shfl_xor(acc.y, 16, 64);
    acc.z += __shfl_xor(acc.z, 16, 64);
    acc.w += __shfl_xor(acc.w, 16, 64);
    acc.x += __shfl_xor(acc.x, 32, 64);
    acc.y += __shfl_xor(acc.y, 32, 64);
    acc.z += __shfl_xor(acc.z, 32, 64);
    acc.w += __shfl_xor(acc.w, 32, 64);

    if (slot == 0) {
        float di = dinv[wid];
        float4 g  = *(const float4*)(G + (size_t)wid * DIM + fc);
        float4 bv = *(const float4*)(bias + fc);
        float4 r;
        r.x = di * (acc.x + g.x) + bv.x;
        r.y = di * (acc.y + g.y) + bv.y;
        r.z = di * (acc.z + g.z) + bv.z;
        r.w = di * (acc.w + g.w) + bv.w;
        r.x = (r.x >= 0.f) ? r.x : NEG_SLOPE * r.x;
        r.y = (r.y >= 0.f) ? r.y : NEG_SLOPE * r.y;
        r.z = (r.z >= 0.f) ? r.z : NEG_SLOPE * r.z;
        r.w = (r.w >= 0.f) ? r.w : NEG_SLOPE * r.w;
        *(float4*)(out + (size_t)wid * DIM + fc) = r;
    }
}

extern "C" void kernel_launch(void* const* d_in, const int* in_sizes, int n_in,
                              void* d_out, int out_size, void* d_ws, size_t ws_size,
                              hipStream_t stream) {
    const float* x = (const float*)d_in[0];
    const int* ei = (const int*)d_in[1];
    const int* src = ei;
    const int* dst = ei + N_EDGES;
    const float* W[4] = {(const float*)d_in[2], (const float*)d_in[4],
                         (const float*)d_in[6], (const float*)d_in[8]};
    const float* b[4] = {(const float*)d_in[3], (const float*)d_in[5],
                         (const float*)d_in[7], (const float*)d_in[9]};
    float* out = (float*)d_out;

    char* ws = (char*)d_ws;
    size_t off = 0;
    auto alloc = [&](size_t bytes) -> void* {
        void* p = ws + off;
        off = (off + bytes + 255) & ~(size_t)255;
        return p;
    };
    float* A      = (float*)alloc((size_t)N_NODES * DIM * sizeof(float));     // 25.6 MB
    int*   csr    = (int*)alloc((size_t)N_EDGES * sizeof(int));               // 6.4 MB
    int*   bdata  = (int*)alloc((size_t)NBUCK * BCAP * sizeof(int));          // 12.8 MB
    int*   gcur   = (int*)alloc((size_t)NBUCK * 16 * sizeof(int));            // 50 KB (64B-padded cursors)
    int*   bbase  = (int*)alloc((size_t)(NBUCK + 1) * sizeof(int));
    int*   offsets= (int*)alloc((size_t)(N_NODES + 1) * sizeof(int));
    float* dinv   = (float*)alloc((size_t)N_NODES * sizeof(float));

    hipMemsetAsync(gcur, 0, (size_t)NBUCK * 16 * sizeof(int), stream);

    bucket_scatter<<<BLOCKS1, 256, 0, stream>>>(src, dst, gcur, bdata);
    bucket_scan<<<1, 1024, 0, stream>>>(gcur, bbase);
    bucket_build<<<NBUCK, 256, 0, stream>>>(bdata, gcur, bbase, offsets, dinv, csr);

    const int MM_GRID  = (N_NODES + 63) / 64;          // 1563
    const int AGG_GRID = (N_NODES * DIM + 255) / 256;  // 25000

    // L1: mm(x)->A, agg(A)->out
    mm_kernel<<<MM_GRID, 256, 0, stream>>>(x, W[0], dinv, A);
    agg_kernel<<<AGG_GRID, 256, 0, stream>>>(A, csr, offsets, dinv, b[0], out);
    // L2: mm(out)->out (in-place), agg(out)->A
    mm_kernel<<<MM_GRID, 256, 0, stream>>>(out, W[1], dinv, out);
    agg_kernel<<<AGG_GRID, 256, 0, stream>>>(out, csr, offsets, dinv, b[1], A);
    // L3: mm(A)->A (in-place), agg(A)->out
    mm_kernel<<<MM_GRID, 256, 0, stream>>>(A, W[2], dinv, A);
    agg_kernel<<<AGG_GRID, 256, 0, stream>>>(A, csr, offsets, dinv, b[2], out);
    // L4: mm(out)->A, agg(A)->out
    mm_kernel<<<MM_GRID, 256, 0, stream>>>(out, W[3], dinv, A);
    agg_kernel<<<AGG_GRID, 256, 0, stream>>>(A, csr, offsets, dinv, b[3], out);
}

// Round 5
// 459.873 us; speedup vs baseline: 1.3890x; 1.0873x over previous
//
#include <hip/hip_runtime.h>

#define N_NODES 100000
#define N_EDGES 1600000
#define DIM 64
#define NEG_SLOPE 0.01f

#define BNODES 128            // nodes per bucket
#define NBUCK 782             // ceil(100000/128)
#define BCAP 4096             // slab capacity per bucket (avg fill ~2046)
#define BLOCKS1 256           // scatter blocks (1 per CU)
#define THREADS1 512
#define EPB ((N_EDGES + BLOCKS1 - 1) / BLOCKS1)   // 6250

// ---- pass 1: bucket scatter. One reservation atomic per (block,bucket). ----
// Entry packing: src (17 bits) | local_dst (7 bits) << 17.
__global__ __launch_bounds__(THREADS1) void bucket_scatter(const int* __restrict__ src,
                                                           const int* __restrict__ dst,
                                                           int* __restrict__ gcur,   // stride 16 (64B pad)
                                                           int* __restrict__ bdata) {
    __shared__ int cnt[NBUCK];
    __shared__ int base[NBUCK];
    const int tid = threadIdx.x;
    for (int i = tid; i < NBUCK; i += THREADS1) cnt[i] = 0;
    __syncthreads();

    const int e0 = blockIdx.x * EPB;
    const int e1 = (e0 + EPB < N_EDGES) ? e0 + EPB : N_EDGES;

    for (int e = e0 + tid; e < e1; e += THREADS1)
        atomicAdd(&cnt[dst[e] >> 7], 1);
    __syncthreads();

    for (int b = tid; b < NBUCK; b += THREADS1) {
        int c = cnt[b];
        base[b] = c ? atomicAdd(&gcur[b * 16], c) : 0;
        cnt[b] = 0;
    }
    __syncthreads();

    for (int e = e0 + tid; e < e1; e += THREADS1) {
        int d = dst[e];
        int b = d >> 7;
        int pos = base[b] + atomicAdd(&cnt[b], 1);
        bdata[(size_t)b * BCAP + pos] = src[e] | ((d & 127) << 17);
    }
}

// ---- exclusive scan of bucket sizes -> bucket csr base ----
__global__ void bucket_scan(const int* __restrict__ gcur, int* __restrict__ bbase) {
    __shared__ int sm[1024];
    const int tid = threadIdx.x;
    int v = (tid < NBUCK) ? gcur[tid * 16] : 0;
    sm[tid] = v;
    __syncthreads();
    for (int s = 1; s < 1024; s <<= 1) {
        int a = ((int)tid >= s) ? sm[tid - s] : 0;
        __syncthreads();
        sm[tid] += a;
        __syncthreads();
    }
    if (tid < NBUCK) bbase[tid] = sm[tid] - v;   // exclusive
}

// ---- pass 2: per-bucket counting sort -> offsets, dinv, csr (single-writer) ----
__global__ __launch_bounds__(256) void bucket_build(const int* __restrict__ bdata,
                                                    const int* __restrict__ gcur,
                                                    const int* __restrict__ bbase,
                                                    int* __restrict__ offsets,
                                                    float* __restrict__ dinv,
                                                    int* __restrict__ csr) {
    __shared__ int cnt[BNODES];
    __shared__ int excl[BNODES];
    const int tid = threadIdx.x;
    const int b = blockIdx.x;
    const int sz = gcur[b * 16];
    const int* bd = bdata + (size_t)b * BCAP;
    const int cbase = bbase[b];

    for (int i = tid; i < BNODES; i += 256) cnt[i] = 0;
    __syncthreads();
    for (int i = tid; i < sz; i += 256)
        atomicAdd(&cnt[bd[i] >> 17], 1);
    __syncthreads();
    if (tid == 0) {
        int run = 0;
        for (int j = 0; j < BNODES; ++j) { excl[j] = run; run += cnt[j]; }
    }
    __syncthreads();

    const int nb = b * BNODES;
    for (int i = tid; i < BNODES; i += 256) {
        int n = nb + i;
        if (n < N_NODES) {
            offsets[n] = cbase + excl[i];
            dinv[n] = rsqrtf((float)(cnt[i] + 1));   // deg incl self-loop
        }
    }
    if (b == NBUCK - 1 && tid == 0) offsets[N_NODES] = N_EDGES;

    for (int i = tid; i < BNODES; i += 256) cnt[i] = 0;   // reuse as cursor
    __syncthreads();
    for (int i = tid; i < sz; i += 256) {
        int v = bd[i];
        int l = v >> 17;
        int pos = cbase + excl[l] + atomicAdd(&cnt[l], 1);
        csr[pos] = v & 0x1FFFF;
    }
}

// ---------------- fp32 matmul + dinv scale: G[i,:] = dinv[i] * (X[i,:] @ W) ----------------
__global__ __launch_bounds__(256) void mm_kernel(const float* X, const float* __restrict__ W,
                                                 const float* __restrict__ dinv, float* G) {
    __shared__ float xs[64][68];
    __shared__ float ws[64][64];
    const int t = threadIdx.x;
    const int rbase = blockIdx.x * 64;

    const float4* Wv = (const float4*)W;
    for (int i = t; i < 1024; i += 256)
        ((float4*)&ws[0][0])[i] = Wv[i];

    for (int i = t; i < 1024; i += 256) {
        int r = i >> 4, kb = i & 15;
        int row = rbase + r;
        float4 xv = make_float4(0.f, 0.f, 0.f, 0.f);
        if (row < N_NODES) xv = *(const float4*)(X + row * DIM + kb * 4);
        *(float4*)&xs[r][kb * 4] = xv;
    }
    __syncthreads();

    const int c4 = (t & 15) * 4;
    const int r0 = t >> 4;
    float4 a0 = make_float4(0.f, 0.f, 0.f, 0.f), a1 = a0, a2 = a0, a3 = a0;

#pragma unroll 4
    for (int kb = 0; kb < 16; ++kb) {
        float x0[4], x1[4], x2[4], x3[4];
        *(float4*)x0 = *(const float4*)&xs[r0][kb * 4];
        *(float4*)x1 = *(const float4*)&xs[r0 + 16][kb * 4];
        *(float4*)x2 = *(const float4*)&xs[r0 + 32][kb * 4];
        *(float4*)x3 = *(const float4*)&xs[r0 + 48][kb * 4];
#pragma unroll
        for (int j = 0; j < 4; ++j) {
            float4 wv = *(const float4*)&ws[kb * 4 + j][c4];
            a0.x = fmaf(x0[j], wv.x, a0.x); a0.y = fmaf(x0[j], wv.y, a0.y);
            a0.z = fmaf(x0[j], wv.z, a0.z); a0.w = fmaf(x0[j], wv.w, a0.w);
            a1.x = fmaf(x1[j], wv.x, a1.x); a1.y = fmaf(x1[j], wv.y, a1.y);
            a1.z = fmaf(x1[j], wv.z, a1.z); a1.w = fmaf(x1[j], wv.w, a1.w);
            a2.x = fmaf(x2[j], wv.x, a2.x); a2.y = fmaf(x2[j], wv.y, a2.y);
            a2.z = fmaf(x2[j], wv.z, a2.z); a2.w = fmaf(x2[j], wv.w, a2.w);
            a3.x = fmaf(x3[j], wv.x, a3.x); a3.y = fmaf(x3[j], wv.y, a3.y);
            a3.z = fmaf(x3[j], wv.z, a3.z); a3.w = fmaf(x3[j], wv.w, a3.w);
        }
    }

    int row;
    row = rbase + r0;
    if (row < N_NODES) {
        float di = dinv[row];
        a0.x *= di; a0.y *= di; a0.z *= di; a0.w *= di;
        *(float4*)(G + row * DIM + c4) = a0;
    }
    row = rbase + r0 + 16;
    if (row < N_NODES) {
        float di = dinv[row];
        a1.x *= di; a1.y *= di; a1.z *= di; a1.w *= di;
        *(float4*)(G + row * DIM + c4) = a1;
    }
    row = rbase + r0 + 32;
    if (row < N_NODES) {
        float di = dinv[row];
        a2.x *= di; a2.y *= di; a2.z *= di; a2.w *= di;
        *(float4*)(G + row * DIM + c4) = a2;
    }
    row = rbase + r0 + 48;
    if (row < N_NODES) {
        float di = dinv[row];
        a3.x *= di; a3.y *= di; a3.z *= di; a3.w *= di;
        *(float4*)(G + row * DIM + c4) = a3;
    }
}

// ---------------- aggregate: wave per node, 8 edges in flight ----------------
// out[d,:] = leakyrelu( dinv[d] * (G[d,:] + sum_{e in N(d)} G[src[e],:]) + b )
// slot = lane>>4 (4 edge slots); 2-deep unroll -> 2 independent row loads per
// slot per iteration (8 rows in flight per wave).
__global__ __launch_bounds__(256) void agg_kernel(const float* __restrict__ G,
                                                  const int* __restrict__ csr,
                                                  const int* __restrict__ offsets,
                                                  const float* __restrict__ dinv,
                                                  const float* __restrict__ bias,
                                                  float* __restrict__ out) {
    int wid = (blockIdx.x * 256 + threadIdx.x) >> 6;   // node id
    if (wid >= N_NODES) return;
    const int lane = threadIdx.x & 63;
    const int slot = lane >> 4;          // 0..3
    const int fc   = (lane & 15) * 4;    // feature chunk base

    const int beg = offsets[wid], end = offsets[wid + 1];
    float4 acc0 = make_float4(0.f, 0.f, 0.f, 0.f);
    float4 acc1 = acc0;

    int e = beg + slot;
    for (; e + 4 < end; e += 8) {
        int p0 = csr[e];
        int p1 = csr[e + 4];
        float4 v0 = *(const float4*)(G + (size_t)p0 * DIM + fc);
        float4 v1 = *(const float4*)(G + (size_t)p1 * DIM + fc);
        acc0.x += v0.x; acc0.y += v0.y; acc0.z += v0.z; acc0.w += v0.w;
        acc1.x += v1.x; acc1.y += v1.y; acc1.z += v1.z; acc1.w += v1.w;
    }
    if (e < end) {
        int p0 = csr[e];
        float4 v0 = *(const float4*)(G + (size_t)p0 * DIM + fc);
        acc0.x += v0.x; acc0.y += v0.y; acc0.z += v0.z; acc0.w += v0.w;
    }
    float4 acc;
    acc.x = acc0.x + acc1.x; acc.y = acc0.y + acc1.y;
    acc.z = acc0.z + acc1.z; acc.w = acc0.w + acc1.w;

    acc.x += __shfl_xor(acc.x, 16, 64);
    acc.y += __shfl_xor(acc.y, 16, 64);
    acc.z += __shfl_xor(acc.z, 16, 64);
    acc.w += __shfl_xor(acc.w, 16, 64);
    acc.x += __shfl_xor(acc.x, 32, 64);
    acc.y += __shfl_xor(acc.y, 32, 64);
    acc.z += __shfl_xor(acc.z, 32, 64);
    acc.w += __shfl_xor(acc.w, 32, 64);

    if (slot == 0) {
        float di = dinv[wid];
        float4 g  = *(const float4*)(G + (size_t)wid * DIM + fc);
        float4 bv = *(const float4*)(bias + fc);
        float4 r;
        r.x = di * (acc.x + g.x) + bv.x;
        r.y = di * (acc.y + g.y) + bv.y;
        r.z = di * (acc.z + g.z) + bv.z;
        r.w = di * (acc.w + g.w) + bv.w;
        r.x = (r.x >= 0.f) ? r.x : NEG_SLOPE * r.x;
        r.y = (r.y >= 0.f) ? r.y : NEG_SLOPE * r.y;
        r.z = (r.z >= 0.f) ? r.z : NEG_SLOPE * r.z;
        r.w = (r.w >= 0.f) ? r.w : NEG_SLOPE * r.w;
        *(float4*)(out + (size_t)wid * DIM + fc) = r;
    }
}

extern "C" void kernel_launch(void* const* d_in, const int* in_sizes, int n_in,
                              void* d_out, int out_size, void* d_ws, size_t ws_size,
                              hipStream_t stream) {
    const float* x = (const float*)d_in[0];
    const int* ei = (const int*)d_in[1];
    const int* src = ei;
    const int* dst = ei + N_EDGES;
    const float* W[4] = {(const float*)d_in[2], (const float*)d_in[4],
                         (const float*)d_in[6], (const float*)d_in[8]};
    const float* b[4] = {(const float*)d_in[3], (const float*)d_in[5],
                         (const float*)d_in[7], (const float*)d_in[9]};
    float* out = (float*)d_out;

    char* ws = (char*)d_ws;
    size_t off = 0;
    auto alloc = [&](size_t bytes) -> void* {
        void* p = ws + off;
        off = (off + bytes + 255) & ~(size_t)255;
        return p;
    };
    float* A      = (float*)alloc((size_t)N_NODES * DIM * sizeof(float));     // 25.6 MB
    int*   csr    = (int*)alloc((size_t)N_EDGES * sizeof(int));               // 6.4 MB
    int*   bdata  = (int*)alloc((size_t)NBUCK * BCAP * sizeof(int));          // 12.8 MB
    int*   gcur   = (int*)alloc((size_t)NBUCK * 16 * sizeof(int));            // 50 KB
    int*   bbase  = (int*)alloc((size_t)(NBUCK + 1) * sizeof(int));
    int*   offsets= (int*)alloc((size_t)(N_NODES + 1) * sizeof(int));
    float* dinv   = (float*)alloc((size_t)N_NODES * sizeof(float));

    hipMemsetAsync(gcur, 0, (size_t)NBUCK * 16 * sizeof(int), stream);

    bucket_scatter<<<BLOCKS1, THREADS1, 0, stream>>>(src, dst, gcur, bdata);
    bucket_scan<<<1, 1024, 0, stream>>>(gcur, bbase);
    bucket_build<<<NBUCK, 256, 0, stream>>>(bdata, gcur, bbase, offsets, dinv, csr);

    const int MM_GRID  = (N_NODES + 63) / 64;          // 1563
    const int AGG_GRID = (N_NODES * DIM + 255) / 256;  // 25000

    // L1: mm(x)->A, agg(A)->out
    mm_kernel<<<MM_GRID, 256, 0, stream>>>(x, W[0], dinv, A);
    agg_kernel<<<AGG_GRID, 256, 0, stream>>>(A, csr, offsets, dinv, b[0], out);
    // L2: mm(out)->out (in-place), agg(out)->A
    mm_kernel<<<MM_GRID, 256, 0, stream>>>(out, W[1], dinv, out);
    agg_kernel<<<AGG_GRID, 256, 0, stream>>>(out, csr, offsets, dinv, b[1], A);
    // L3: mm(A)->A (in-place), agg(A)->out
    mm_kernel<<<MM_GRID, 256, 0, stream>>>(A, W[2], dinv, A);
    agg_kernel<<<AGG_GRID, 256, 0, stream>>>(A, csr, offsets, dinv, b[2], out);
    // L4: mm(out)->A, agg(A)->out
    mm_kernel<<<MM_GRID, 256, 0, stream>>>(out, W[3], dinv, A);
    agg_kernel<<<AGG_GRID, 256, 0, stream>>>(A, csr, offsets, dinv, b[3], out);
}

// Round 7
// 386.055 us; speedup vs baseline: 1.6546x; 1.1912x over previous
//
#include <hip/hip_runtime.h>
#include <hip/hip_fp16.h>

#define N_NODES 100000
#define N_EDGES 1600000
#define DIM 64
#define NEG_SLOPE 0.01f

#define BNODES 128            // nodes per bucket
#define NBUCK 782             // ceil(100000/128)
#define BCAP 4096             // slab capacity per bucket (avg fill ~2046)
#define BLOCKS1 256           // scatter blocks (1 per CU)
#define THREADS1 512
#define EPB ((N_EDGES + BLOCKS1 - 1) / BLOCKS1)   // 6250

// ---- pass 1: bucket scatter. One reservation atomic per (block,bucket). ----
// Entry packing: src (17 bits) | local_dst (7 bits) << 17.
__global__ __launch_bounds__(THREADS1) void bucket_scatter(const int* __restrict__ src,
                                                           const int* __restrict__ dst,
                                                           int* __restrict__ gcur,   // stride 16 (64B pad)
                                                           int* __restrict__ bdata) {
    __shared__ int cnt[NBUCK];
    __shared__ int base[NBUCK];
    const int tid = threadIdx.x;
    for (int i = tid; i < NBUCK; i += THREADS1) cnt[i] = 0;
    __syncthreads();

    const int e0 = blockIdx.x * EPB;
    const int e1 = (e0 + EPB < N_EDGES) ? e0 + EPB : N_EDGES;

    for (int e = e0 + tid; e < e1; e += THREADS1)
        atomicAdd(&cnt[dst[e] >> 7], 1);
    __syncthreads();

    for (int b = tid; b < NBUCK; b += THREADS1) {
        int c = cnt[b];
        base[b] = c ? atomicAdd(&gcur[b * 16], c) : 0;
        cnt[b] = 0;
    }
    __syncthreads();

    for (int e = e0 + tid; e < e1; e += THREADS1) {
        int d = dst[e];
        int b = d >> 7;
        int pos = base[b] + atomicAdd(&cnt[b], 1);
        bdata[(size_t)b * BCAP + pos] = src[e] | ((d & 127) << 17);
    }
}

// ---- exclusive scan of bucket sizes -> bucket csr base ----
__global__ void bucket_scan(const int* __restrict__ gcur, int* __restrict__ bbase) {
    __shared__ int sm[1024];
    const int tid = threadIdx.x;
    int v = (tid < NBUCK) ? gcur[tid * 16] : 0;
    sm[tid] = v;
    __syncthreads();
    for (int s = 1; s < 1024; s <<= 1) {
        int a = ((int)tid >= s) ? sm[tid - s] : 0;
        __syncthreads();
        sm[tid] += a;
        __syncthreads();
    }
    if (tid < NBUCK) bbase[tid] = sm[tid] - v;   // exclusive
}

// ---- pass 2: per-bucket counting sort -> offsets, dinv, csr (single-writer) ----
__global__ __launch_bounds__(256) void bucket_build(const int* __restrict__ bdata,
                                                    const int* __restrict__ gcur,
                                                    const int* __restrict__ bbase,
                                                    int* __restrict__ offsets,
                                                    float* __restrict__ dinv,
                                                    int* __restrict__ csr) {
    __shared__ int cnt[BNODES];
    __shared__ int excl[BNODES];
    const int tid = threadIdx.x;
    const int b = blockIdx.x;
    const int sz = gcur[b * 16];
    const int* bd = bdata + (size_t)b * BCAP;
    const int cbase = bbase[b];

    for (int i = tid; i < BNODES; i += 256) cnt[i] = 0;
    __syncthreads();
    for (int i = tid; i < sz; i += 256)
        atomicAdd(&cnt[bd[i] >> 17], 1);
    __syncthreads();
    if (tid == 0) {
        int run = 0;
        for (int j = 0; j < BNODES; ++j) { excl[j] = run; run += cnt[j]; }
    }
    __syncthreads();

    const int nb = b * BNODES;
    for (int i = tid; i < BNODES; i += 256) {
        int n = nb + i;
        if (n < N_NODES) {
            offsets[n] = cbase + excl[i];
            dinv[n] = rsqrtf((float)(cnt[i] + 1));   // deg incl self-loop
        }
    }
    if (b == NBUCK - 1 && tid == 0) offsets[N_NODES] = N_EDGES;

    for (int i = tid; i < BNODES; i += 256) cnt[i] = 0;   // reuse as cursor
    __syncthreads();
    for (int i = tid; i < sz; i += 256) {
        int v = bd[i];
        int l = v >> 17;
        int pos = cbase + excl[l] + atomicAdd(&cnt[l], 1);
        csr[pos] = v & 0x1FFFF;
    }
}

// ---- fp32 matmul + dinv scale, fp16 output: G16[i,:] = (half) dinv[i]*(X[i,:]@W) ----
__global__ __launch_bounds__(256) void mm_kernel(const float* __restrict__ X,
                                                 const float* __restrict__ W,
                                                 const float* __restrict__ dinv,
                                                 __half* __restrict__ G16) {
    __shared__ float xs[64][68];
    __shared__ float ws[64][64];
    const int t = threadIdx.x;
    const int rbase = blockIdx.x * 64;

    const float4* Wv = (const float4*)W;
    for (int i = t; i < 1024; i += 256)
        ((float4*)&ws[0][0])[i] = Wv[i];

    for (int i = t; i < 1024; i += 256) {
        int r = i >> 4, kb = i & 15;
        int row = rbase + r;
        float4 xv = make_float4(0.f, 0.f, 0.f, 0.f);
        if (row < N_NODES) xv = *(const float4*)(X + row * DIM + kb * 4);
        *(float4*)&xs[r][kb * 4] = xv;
    }
    __syncthreads();

    const int c4 = (t & 15) * 4;
    const int r0 = t >> 4;
    float4 a0 = make_float4(0.f, 0.f, 0.f, 0.f), a1 = a0, a2 = a0, a3 = a0;

#pragma unroll 4
    for (int kb = 0; kb < 16; ++kb) {
        float x0[4], x1[4], x2[4], x3[4];
        *(float4*)x0 = *(const float4*)&xs[r0][kb * 4];
        *(float4*)x1 = *(const float4*)&xs[r0 + 16][kb * 4];
        *(float4*)x2 = *(const float4*)&xs[r0 + 32][kb * 4];
        *(float4*)x3 = *(const float4*)&xs[r0 + 48][kb * 4];
#pragma unroll
        for (int j = 0; j < 4; ++j) {
            float4 wv = *(const float4*)&ws[kb * 4 + j][c4];
            a0.x = fmaf(x0[j], wv.x, a0.x); a0.y = fmaf(x0[j], wv.y, a0.y);
            a0.z = fmaf(x0[j], wv.z, a0.z); a0.w = fmaf(x0[j], wv.w, a0.w);
            a1.x = fmaf(x1[j], wv.x, a1.x); a1.y = fmaf(x1[j], wv.y, a1.y);
            a1.z = fmaf(x1[j], wv.z, a1.z); a1.w = fmaf(x1[j], wv.w, a1.w);
            a2.x = fmaf(x2[j], wv.x, a2.x); a2.y = fmaf(x2[j], wv.y, a2.y);
            a2.z = fmaf(x2[j], wv.z, a2.z); a2.w = fmaf(x2[j], wv.w, a2.w);
            a3.x = fmaf(x3[j], wv.x, a3.x); a3.y = fmaf(x3[j], wv.y, a3.y);
            a3.z = fmaf(x3[j], wv.z, a3.z); a3.w = fmaf(x3[j], wv.w, a3.w);
        }
    }

#define STORE_ROW(acc, roff)                                            \
    {                                                                   \
        int row = rbase + r0 + (roff);                                  \
        if (row < N_NODES) {                                            \
            float di = dinv[row];                                       \
            __half2 p0 = __floats2half2_rn(di * (acc).x, di * (acc).y); \
            __half2 p1 = __floats2half2_rn(di * (acc).z, di * (acc).w); \
            uint2 u;                                                    \
            u.x = *(unsigned int*)&p0;                                  \
            u.y = *(unsigned int*)&p1;                                  \
            *(uint2*)(G16 + (size_t)row * DIM + c4) = u;                \
        }                                                               \
    }
    STORE_ROW(a0, 0)
    STORE_ROW(a1, 16)
    STORE_ROW(a2, 32)
    STORE_ROW(a3, 48)
#undef STORE_ROW
}

// ---------------- aggregate: wave per node, fp16 rows, 16 edges in flight ----------------
// out[d,:] = leakyrelu( dinv[d] * (G[d,:] + sum_{e in N(d)} G[src[e],:]) + b )
// Row = 64 fp16 = 128 B. 8 lanes cover a row (16 B each) -> slot = lane>>3
// gives 8 edges per load instruction; 2-deep unroll -> 16 rows in flight.
// Self-loop row added in the slot==0 epilogue AFTER the cross-slot reduction
// (adding it pre-reduction counts it 8x — the R6 bug).
__global__ __launch_bounds__(256) void agg_kernel(const __half* __restrict__ G16,
                                                  const int* __restrict__ csr,
                                                  const int* __restrict__ offsets,
                                                  const float* __restrict__ dinv,
                                                  const float* __restrict__ bias,
                                                  float* __restrict__ out) {
    int wid = (blockIdx.x * 256 + threadIdx.x) >> 6;   // node id
    if (wid >= N_NODES) return;
    const int lane = threadIdx.x & 63;
    const int slot = lane >> 3;          // 0..7
    const int sub  = lane & 7;           // 16B chunk within row
    const int fc   = sub * 8;            // first feature of this lane's chunk

    const int beg = offsets[wid], end = offsets[wid + 1];

    float acc[8];
#pragma unroll
    for (int k = 0; k < 8; ++k) acc[k] = 0.f;

#define ACCUM(vraw)                                         \
    {                                                       \
        const __half2* hp = (const __half2*)&(vraw);        \
        float2 f0 = __half22float2(hp[0]);                  \
        float2 f1 = __half22float2(hp[1]);                  \
        float2 f2 = __half22float2(hp[2]);                  \
        float2 f3 = __half22float2(hp[3]);                  \
        acc[0] += f0.x; acc[1] += f0.y;                     \
        acc[2] += f1.x; acc[3] += f1.y;                     \
        acc[4] += f2.x; acc[5] += f2.y;                     \
        acc[6] += f3.x; acc[7] += f3.y;                     \
    }

    int e = beg + slot;
    for (; e + 8 < end; e += 16) {
        int p0 = csr[e];
        int p1 = csr[e + 8];
        float4 v0 = *(const float4*)(G16 + (size_t)p0 * DIM + fc);
        float4 v1 = *(const float4*)(G16 + (size_t)p1 * DIM + fc);
        ACCUM(v0)
        ACCUM(v1)
    }
    if (e < end) {
        int p0 = csr[e];
        float4 v0 = *(const float4*)(G16 + (size_t)p0 * DIM + fc);
        ACCUM(v0)
    }

    // reduce across the 8 slots (lane bits 3,4,5)
#pragma unroll
    for (int k = 0; k < 8; ++k) {
        acc[k] += __shfl_xor(acc[k], 8, 64);
        acc[k] += __shfl_xor(acc[k], 16, 64);
        acc[k] += __shfl_xor(acc[k], 32, 64);
    }

    if (slot == 0) {   // lanes 0..7 hold features fc..fc+7
        // self-loop row: add exactly once, post-reduction
        float4 vs = *(const float4*)(G16 + (size_t)wid * DIM + fc);
        ACCUM(vs)

        float di = dinv[wid];
        float4 b0 = *(const float4*)(bias + fc);
        float4 b1 = *(const float4*)(bias + fc + 4);
        float4 r0, r1;
        r0.x = di * acc[0] + b0.x;
        r0.y = di * acc[1] + b0.y;
        r0.z = di * acc[2] + b0.z;
        r0.w = di * acc[3] + b0.w;
        r1.x = di * acc[4] + b1.x;
        r1.y = di * acc[5] + b1.y;
        r1.z = di * acc[6] + b1.z;
        r1.w = di * acc[7] + b1.w;
        r0.x = (r0.x >= 0.f) ? r0.x : NEG_SLOPE * r0.x;
        r0.y = (r0.y >= 0.f) ? r0.y : NEG_SLOPE * r0.y;
        r0.z = (r0.z >= 0.f) ? r0.z : NEG_SLOPE * r0.z;
        r0.w = (r0.w >= 0.f) ? r0.w : NEG_SLOPE * r0.w;
        r1.x = (r1.x >= 0.f) ? r1.x : NEG_SLOPE * r1.x;
        r1.y = (r1.y >= 0.f) ? r1.y : NEG_SLOPE * r1.y;
        r1.z = (r1.z >= 0.f) ? r1.z : NEG_SLOPE * r1.z;
        r1.w = (r1.w >= 0.f) ? r1.w : NEG_SLOPE * r1.w;
        *(float4*)(out + (size_t)wid * DIM + fc) = r0;
        *(float4*)(out + (size_t)wid * DIM + fc + 4) = r1;
    }
#undef ACCUM
}

extern "C" void kernel_launch(void* const* d_in, const int* in_sizes, int n_in,
                              void* d_out, int out_size, void* d_ws, size_t ws_size,
                              hipStream_t stream) {
    const float* x = (const float*)d_in[0];
    const int* ei = (const int*)d_in[1];
    const int* src = ei;
    const int* dst = ei + N_EDGES;
    const float* W[4] = {(const float*)d_in[2], (const float*)d_in[4],
                         (const float*)d_in[6], (const float*)d_in[8]};
    const float* b[4] = {(const float*)d_in[3], (const float*)d_in[5],
                         (const float*)d_in[7], (const float*)d_in[9]};
    float* out = (float*)d_out;

    char* ws = (char*)d_ws;
    size_t off = 0;
    auto alloc = [&](size_t bytes) -> void* {
        void* p = ws + off;
        off = (off + bytes + 255) & ~(size_t)255;
        return p;
    };
    __half* G16   = (__half*)alloc((size_t)N_NODES * DIM * sizeof(__half));   // 12.8 MB
    int*   csr    = (int*)alloc((size_t)N_EDGES * sizeof(int));               // 6.4 MB
    int*   bdata  = (int*)alloc((size_t)NBUCK * BCAP * sizeof(int));          // 12.8 MB
    int*   gcur   = (int*)alloc((size_t)NBUCK * 16 * sizeof(int));            // 50 KB
    int*   bbase  = (int*)alloc((size_t)(NBUCK + 1) * sizeof(int));
    int*   offsets= (int*)alloc((size_t)(N_NODES + 1) * sizeof(int));
    float* dinv   = (float*)alloc((size_t)N_NODES * sizeof(float));

    hipMemsetAsync(gcur, 0, (size_t)NBUCK * 16 * sizeof(int), stream);

    bucket_scatter<<<BLOCKS1, THREADS1, 0, stream>>>(src, dst, gcur, bdata);
    bucket_scan<<<1, 1024, 0, stream>>>(gcur, bbase);
    bucket_build<<<NBUCK, 256, 0, stream>>>(bdata, gcur, bbase, offsets, dinv, csr);

    const int MM_GRID  = (N_NODES + 63) / 64;          // 1563
    const int AGG_GRID = (N_NODES * DIM + 255) / 256;  // 25000

    // activation lives in d_out (fp32); G16 is the fp16 gather buffer
    mm_kernel<<<MM_GRID, 256, 0, stream>>>(x, W[0], dinv, G16);
    agg_kernel<<<AGG_GRID, 256, 0, stream>>>(G16, csr, offsets, dinv, b[0], out);
    mm_kernel<<<MM_GRID, 256, 0, stream>>>(out, W[1], dinv, G16);
    agg_kernel<<<AGG_GRID, 256, 0, stream>>>(G16, csr, offsets, dinv, b[1], out);
    mm_kernel<<<MM_GRID, 256, 0, stream>>>(out, W[2], dinv, G16);
    agg_kernel<<<AGG_GRID, 256, 0, stream>>>(G16, csr, offsets, dinv, b[2], out);
    mm_kernel<<<MM_GRID, 256, 0, stream>>>(out, W[3], dinv, G16);
    agg_kernel<<<AGG_GRID, 256, 0, stream>>>(G16, csr, offsets, dinv, b[3], out);
}